// Round 3
// baseline (3585.040 us; speedup 1.0000x reference)
//
#include <hip/hip_runtime.h>
#include <stdint.h>

#define HH   128
#define NLAY 3
#define RR   32
#define OO   48
#define BBX  64
#define FFX  32
#define LLX  (RR + OO - 1)    /* 79 */
#define RBr  (RR * BBX)       /* 2048 */
#define N6   (6 * HH)         /* 768 */
#define TSTEPS (LLX + NLAY - 1)  /* 81 */
#define NBLOCKS 192

typedef unsigned short u16;
typedef __attribute__((ext_vector_type(8))) short short8;
typedef __attribute__((ext_vector_type(4))) float f32x4;

// ---- workspace layout (bytes, all 256-aligned by construction) ----
#define OFF_ABUF0 ((size_t)0)
#define SZ_ABUF0  ((size_t)LLX * RBr * FFX * 2)        /* 10,354,688 */
#define OFF_HZ    (OFF_ABUF0 + SZ_ABUF0)
#define SZ_HZ     ((size_t)NLAY * 2 * RBr * 256 * 2)   /* [l][slot][2048][256] bf16 */
#define OFF_HROW  (OFF_HZ + SZ_HZ)
#define SZ_HROW   ((size_t)NLAY * RBr * HH * 4)        /* [l][2048][128] f32 */
#define OFF_HCOL  (OFF_HROW + SZ_HROW)
#define SZ_HCOL   ((size_t)NLAY * 2 * RBr * HH * 4)    /* [l][slot][2048][128] f32 */
#define OFF_BAR   (OFF_HCOL + SZ_HCOL)
#define SZ_BAR    ((size_t)256)
#define SZ_STATE  (SZ_HZ + SZ_HROW + SZ_HCOL + SZ_BAR) /* zeroed every call */
#define OFF_ACTV  (OFF_BAR + SZ_BAR)
#define SZ_ACTV   ((size_t)2 * 2 * RBr * 256 * 2)      /* [pair][slot][2048][256] bf16 */

__device__ __forceinline__ u16 f2b(float x) {
  uint32_t u = __float_as_uint(x);
  return (u16)((u + 0x7FFFu + ((u >> 16) & 1u)) >> 16);
}
__device__ __forceinline__ float sigmoidf_(float x) {
  return 1.0f / (1.0f + __expf(-x));
}
__device__ __forceinline__ float tanhf_(float x) {
  float e = __expf(2.0f * x);
  return 1.0f - 2.0f / (e + 1.0f);
}

// ---------------- prep: wavefront-shifted bf16 input ----------------
__global__ __launch_bounds__(256) void k_prep_input(const float* __restrict__ inp,
                                                    u16* __restrict__ abuf0) {
  int idx = blockIdx.x * 256 + threadIdx.x;
  if (idx >= LLX * RBr * FFX) return;
  int f   = idx & (FFX - 1);
  int row = (idx >> 5) & (RBr - 1);
  int s   = idx / (RBr * FFX);
  int g = row >> 6, b = row & 63;
  int o = s - g;
  float v = (o >= 0 && o < OO) ? inp[((b * RR + g) * OO + o) * FFX + f] : 0.0f;
  abuf0[idx] = f2b(v);
}

// ---------------- zero recurrent state + barrier counter ----------------
__global__ __launch_bounds__(256) void k_zero(uint32_t* __restrict__ p, size_t nwords) {
  size_t i = (size_t)blockIdx.x * 256 + threadIdx.x;
  size_t stride = (size_t)gridDim.x * 256;
  for (; i < nwords; i += stride) p[i] = 0u;
}

// ---------------- device-scope grid barrier (monotonic counter) ----------
__device__ __forceinline__ void grid_barrier(uint32_t* bar, uint32_t target) {
  __syncthreads();
  if (threadIdx.x == 0) {
    __threadfence();  // release: write back this XCD's L2
    __hip_atomic_fetch_add(bar, 1u, __ATOMIC_ACQ_REL, __HIP_MEMORY_SCOPE_AGENT);
    while (__hip_atomic_load(bar, __ATOMIC_ACQUIRE, __HIP_MEMORY_SCOPE_AGENT) < target)
      __builtin_amdgcn_s_sleep(2);
    __threadfence();  // acquire: invalidate L1 + this XCD's L2
  }
  __syncthreads();
}

// ---------------- persistent body for one (layer,jblk,rowblk) block -------
template <int KK>
__device__ __forceinline__ void persist_body(char* __restrict__ ws,
                                             const float* __restrict__ Wsrc,
                                             const float* __restrict__ Bias_l,
                                             float* __restrict__ out,
                                             int layer, int rowblk, int jblk,
                                             u16* __restrict__ Wl) {
  constexpr int KA  = KK - 256;   // 32 (layer0) or 256
  constexpr int NCH = KK / 32;    // 9 or 16
  constexpr int LDW = KK + 8;     // pad: 8-group bank spread on b128 reads
  const int tid = threadIdx.x;

  // ---- stage W slice (96 rows x KK) f32 -> bf16 into LDS, once ----
  for (int e = tid; e < 96 * KK; e += 512) {
    int wr = e / KK, k = e - wr * KK;
    int srow = (wr >> 4) * 128 + jblk * 16 + (wr & 15);   // gate m, hidden j
    Wl[wr * LDW + k] = f2b(Wsrc[(size_t)srow * KK + k]);
  }
  __syncthreads();

  const int lane = tid & 63, w = tid >> 6;
  const int fr = lane & 15, kg = (lane >> 4) << 3;
  const int rsub = (lane >> 4) << 2;
  const int j = jblk * 16 + fr;             // hidden index this lane owns
  const int ra = rowblk * 256 + w * 32;     // wave's row base

  float bia[6];
#pragma unroll
  for (int m = 0; m < 6; ++m) bia[m] = Bias_l[m * 128 + j];

  u16*   hz_base   = (u16*)(ws + OFF_HZ) + (size_t)layer * 2 * RBr * 256;
  float* hrow      = (float*)(ws + OFF_HROW) + (size_t)layer * RBr * HH;
  float* hcol_base = (float*)(ws + OFF_HCOL) + (size_t)layer * 2 * RBr * HH;
  u16*   actv      = (u16*)(ws + OFF_ACTV);
  u16*   abuf0     = (u16*)(ws + OFF_ABUF0);
  uint32_t* bar    = (uint32_t*)(ws + OFF_BAR);
  float* hid_row   = out + (size_t)RBr * LLX * 256;
  float* hid_col   = hid_row + (size_t)BBX * NLAY * RR * HH;

  for (int t = 0; t < TSTEPS; ++t) {
    const int s = t - layer;
    if (s >= 0 && s < LLX) {
      const int sW = s & 1, sR = sW ^ 1;
      const u16*   hzR   = hz_base + (size_t)sR * RBr * 256;
      u16*         hzW   = hz_base + (size_t)sW * RBr * 256;
      const float* hcolR = hcol_base + (size_t)sR * RBr * HH;
      float*       hcolW = hcol_base + (size_t)sW * RBr * HH;
      const u16* asrc;
      if constexpr (KK == 288) asrc = abuf0 + (size_t)s * RBr * FFX;
      else                     asrc = actv + (size_t)((layer - 1) * 2 + sW) * RBr * 256;
      u16* actvO = actv + (size_t)(layer * 2 + sW) * RBr * 256;

      // ---- GEMM: 32 rows x 96 cols per wave, W from LDS, A from global ----
      f32x4 z4 = {0.f, 0.f, 0.f, 0.f};
      f32x4 acc[2][6];
#pragma unroll
      for (int rf = 0; rf < 2; ++rf)
#pragma unroll
        for (int m = 0; m < 6; ++m) acc[rf][m] = z4;

#pragma unroll
      for (int kc = 0; kc < NCH; ++kc) {
        const int col = kc * 32 + kg;
        short8 a0, a1;
        if (col < 256) {
          a0 = *(const short8*)&hzR[(ra + fr) * 256 + col];
          a1 = *(const short8*)&hzR[(ra + 16 + fr) * 256 + col];
        } else {
          a0 = *(const short8*)&asrc[(ra + fr) * KA + (col - 256)];
          a1 = *(const short8*)&asrc[(ra + 16 + fr) * KA + (col - 256)];
        }
#pragma unroll
        for (int m = 0; m < 6; ++m) {
          short8 bv = *(const short8*)&Wl[(m * 16 + fr) * LDW + kc * 32 + kg];
          acc[0][m] = __builtin_amdgcn_mfma_f32_16x16x32_bf16(a0, bv, acc[0][m], 0, 0, 0);
          acc[1][m] = __builtin_amdgcn_mfma_f32_16x16x32_bf16(a1, bv, acc[1][m], 0, 0, 0);
        }
      }

      // ---- fused pointwise epilogue ----
#pragma unroll
      for (int rf = 0; rf < 2; ++rf) {
#pragma unroll
        for (int q = 0; q < 4; ++q) {
          int row = ra + rf * 16 + rsub + q;   // C layout: row=(lane>>4)*4+reg
          int g = row >> 6, b = row & 63;
          float msk = (g <= s && s < RR) ? 1.0f : 0.0f;
          float ur  = sigmoidf_(acc[rf][0][q] + msk * bia[0]);
          float orw = sigmoidf_(acc[rf][1][q] + msk * bia[1]);
          float uc  = sigmoidf_(acc[rf][2][q] + msk * bia[2]);
          float oc  = sigmoidf_(acc[rf][3][q] + msk * bia[3]);
          float ir  = tanhf_(acc[rf][4][q] + msk * bia[4]);
          float ic  = tanhf_(acc[rf][5][q] + msk * bia[5]);
          float hr_o = hrow[row * HH + j];
          float hc_o = hcolR[row * HH + j];
          float hr_n = tanhf_((1.0f - ur) * hr_o + ur * ir) * orw;
          float hc_n = tanhf_((1.0f - uc) * hc_o + uc * ic) * oc;
          hrow[row * HH + j] = hr_n;
          int rp = (((g + 1) & (RR - 1)) << 6) + b;   // col hidden rolls to next group
          hcolW[rp * HH + j] = hc_n;
          hzW[row * 256 + j] = f2b(hr_n);
          hzW[rp * 256 + HH + j] = f2b(hc_n);
          if (layer == 2) {
            out[((size_t)row * LLX + s) * 256 + j] = hr_n;
            out[((size_t)row * LLX + s) * 256 + HH + j] = hc_n;
          } else {
            actvO[row * 256 + j] = f2b(hr_n);
            actvO[row * 256 + HH + j] = f2b(hc_n);
          }
          if (s - g == OO - 1)
            hid_row[((size_t)(b * NLAY + layer) * RR + g) * HH + j] = hr_n;
          if (g == RR - 1 && s >= RR - 1)
            hid_col[((size_t)(b * NLAY + layer) * OO + (s - (RR - 1))) * HH + j] = hc_n;
        }
      }
    }
    grid_barrier(bar, (uint32_t)NBLOCKS * (uint32_t)(t + 1));
  }
}

// ---------------- the persistent kernel ----------------
__global__ __launch_bounds__(512) void k_persist(char* __restrict__ ws,
                                                 const float* __restrict__ Wf,
                                                 const float* __restrict__ Wo,
                                                 const float* __restrict__ Bias,
                                                 float* __restrict__ out) {
  __shared__ u16 Wl[96 * 520];   // 99,840 B; 1 block/CU by LDS capacity
  const int bx = blockIdx.x;
  const int layer = bx >> 6;      // 64 blocks per layer
  const int sub = bx & 63;
  const int rowblk = sub >> 3, jblk = sub & 7;
  const float* bias_l = Bias + layer * N6;
  if (layer == 0) {
    persist_body<288>(ws, Wf, bias_l, out, 0, rowblk, jblk, Wl);
  } else {
    const float* Wsrc = Wo + (size_t)(layer - 1) * N6 * 512;
    persist_body<512>(ws, Wsrc, bias_l, out, layer, rowblk, jblk, Wl);
  }
}

extern "C" void kernel_launch(void* const* d_in, const int* in_sizes, int n_in,
                              void* d_out, int out_size, void* d_ws, size_t ws_size,
                              hipStream_t stream) {
  const float* inp  = (const float*)d_in[0];
  const float* Wf   = (const float*)d_in[1];
  const float* Wo   = (const float*)d_in[2];
  const float* Bias = (const float*)d_in[3];
  float* out = (float*)d_out;
  char* ws = (char*)d_ws;
  (void)in_sizes; (void)n_in; (void)out_size; (void)ws_size;

  k_prep_input<<<(LLX * RBr * FFX) / 256, 256, 0, stream>>>(inp, (u16*)(ws + OFF_ABUF0));
  k_zero<<<2048, 256, 0, stream>>>((uint32_t*)(ws + OFF_HZ), SZ_STATE / 4);
  k_persist<<<NBLOCKS, 512, 0, stream>>>(ws, Wf, Wo, Bias, out);
}

// Round 4
// 3089.850 us; speedup vs baseline: 1.1603x; 1.1603x over previous
//
#include <hip/hip_runtime.h>
#include <stdint.h>

#define HH   128
#define NLAY 3
#define RR   32
#define OO   48
#define BBX  64
#define FFX  32
#define LLX  (RR + OO - 1)    /* 79 */
#define RBr  (RR * BBX)       /* 2048 */
#define N6   (6 * HH)         /* 768 */
#define TSTEPS (LLX + NLAY - 1)  /* 81 */
#define NBLOCKS 192

typedef unsigned short u16;
typedef __attribute__((ext_vector_type(8))) short short8;
typedef __attribute__((ext_vector_type(4))) float f32x4;

// ---- workspace layout (bytes, 256-aligned by construction) ----
#define OFF_ABUF0 ((size_t)0)
#define SZ_ABUF0  ((size_t)LLX * RBr * FFX * 2)
#define OFF_HZ    (OFF_ABUF0 + SZ_ABUF0)
#define SZ_HZ     ((size_t)NLAY * 2 * RBr * 256 * 2)   /* [l][slot][2048][256] bf16 */
#define OFF_HCOL  (OFF_HZ + SZ_HZ)
#define SZ_HCOL   ((size_t)NLAY * 2 * RBr * HH * 4)    /* [l][slot][2048][128] f32 */
#define OFF_BAR   (OFF_HCOL + SZ_HCOL)
#define SZ_BAR    ((size_t)256)
#define SZ_STATE  (SZ_HZ + SZ_HCOL + SZ_BAR)           /* contiguous zero region */
#define OFF_ACTV  (OFF_BAR + SZ_BAR)
#define SZ_ACTV   ((size_t)2 * 2 * RBr * 256 * 2)      /* [pair][slot][2048][256] bf16 */

__device__ __forceinline__ u16 f2b(float x) {
  uint32_t u = __float_as_uint(x);
  return (u16)((u + 0x7FFFu + ((u >> 16) & 1u)) >> 16);
}
__device__ __forceinline__ float sigmoidf_(float x) {
  return 1.0f / (1.0f + __expf(-x));
}
__device__ __forceinline__ float tanhf_(float x) {
  float e = __expf(2.0f * x);
  return 1.0f - 2.0f / (e + 1.0f);
}

// ---------------- prep: wavefront-shifted bf16 input ----------------
__global__ __launch_bounds__(256) void k_prep_input(const float* __restrict__ inp,
                                                    u16* __restrict__ abuf0) {
  int idx = blockIdx.x * 256 + threadIdx.x;
  if (idx >= LLX * RBr * FFX) return;
  int f   = idx & (FFX - 1);
  int row = (idx >> 5) & (RBr - 1);
  int s   = idx / (RBr * FFX);
  int g = row >> 6, b = row & 63;
  int o = s - g;
  float v = (o >= 0 && o < OO) ? inp[((b * RR + g) * OO + o) * FFX + f] : 0.0f;
  abuf0[idx] = f2b(v);
}

// ---------------- zero recurrent state + barrier counter ----------------
__global__ __launch_bounds__(256) void k_zero(uint32_t* __restrict__ p, size_t nwords) {
  size_t i = (size_t)blockIdx.x * 256 + threadIdx.x;
  size_t stride = (size_t)gridDim.x * 256;
  for (; i < nwords; i += stride) p[i] = 0u;
}

// ---------------- device-scope grid barrier (monotonic counter) ----------
__device__ __forceinline__ void grid_barrier(uint32_t* bar, uint32_t target) {
  __syncthreads();
  if (threadIdx.x == 0) {
    __threadfence();
    __hip_atomic_fetch_add(bar, 1u, __ATOMIC_ACQ_REL, __HIP_MEMORY_SCOPE_AGENT);
    while (__hip_atomic_load(bar, __ATOMIC_ACQUIRE, __HIP_MEMORY_SCOPE_AGENT) < target)
      __builtin_amdgcn_s_sleep(2);
    __threadfence();
  }
  __syncthreads();
}

// ---------------- persistent body for one (layer,jblk,rowblk) block -------
template <int KK>
__device__ __forceinline__ void persist_body(char* __restrict__ ws,
                                             const float* __restrict__ Wsrc,
                                             const float* __restrict__ Bias_l,
                                             float* __restrict__ out,
                                             int layer, int rowblk, int jblk,
                                             u16* __restrict__ Wl) {
  constexpr int KA    = KK - 256;           // 32 (layer0) or 256
  constexpr int NCH   = KK / 32;            // 9 or 16
  constexpr int SLOTS = KK / 8;             // 16B slots per W row: 36 or 64
  constexpr int SLP   = (KK == 512) ? 64 : 40;  // padded row stride (slots)
  const int tid = threadIdx.x;

  // ---- stage W slice (96 rows x KK) f32 -> bf16 into LDS, XOR-swizzled ----
  for (int e = tid; e < 96 * SLOTS; e += 512) {
    int wr = e / SLOTS, sl = e - wr * SLOTS;
    int srow = (wr >> 4) * 128 + jblk * 16 + (wr & 15);   // gate m, hidden j
    const float* src = Wsrc + (size_t)srow * KK + sl * 8;
    short8 v;
#pragma unroll
    for (int x = 0; x < 8; ++x) v[x] = (short)f2b(src[x]);
    *(short8*)&Wl[((size_t)wr * SLP + (sl ^ (wr & 7))) * 8] = v;
  }
  __syncthreads();

  const int lane = tid & 63, w = tid >> 6;
  const int fr = lane & 15, hi = lane >> 4, fx = fr & 7;
  const int rsub = hi << 2;
  const int j = jblk * 16 + fr;             // hidden index this lane owns
  const int ra = rowblk * 256 + w * 32;     // wave's row base

  float bia[6];
#pragma unroll
  for (int m = 0; m < 6; ++m) bia[m] = Bias_l[m * 128 + j];

  u16*   hz_base   = (u16*)(ws + OFF_HZ) + (size_t)layer * 2 * RBr * 256;
  float* hcol_base = (float*)(ws + OFF_HCOL) + (size_t)layer * 2 * RBr * HH;
  u16*   actv      = (u16*)(ws + OFF_ACTV);
  u16*   abuf0     = (u16*)(ws + OFF_ABUF0);
  uint32_t* bar    = (uint32_t*)(ws + OFF_BAR);
  float* hid_row   = out + (size_t)RBr * LLX * 256;
  float* hid_col   = hid_row + (size_t)BBX * NLAY * RR * HH;

  float hr_reg[2][4];                       // h_row state lives in registers
#pragma unroll
  for (int rf = 0; rf < 2; ++rf)
#pragma unroll
    for (int q = 0; q < 4; ++q) hr_reg[rf][q] = 0.0f;

  for (int t = 0; t < TSTEPS; ++t) {
    const int s = t - layer;
    if (s >= 0 && s < LLX) {
      const int sW = s & 1, sR = sW ^ 1;
      const u16*   hzR   = hz_base + (size_t)sR * RBr * 256;
      u16*         hzW   = hz_base + (size_t)sW * RBr * 256;
      const float* hcolR = hcol_base + (size_t)sR * RBr * HH;
      float*       hcolW = hcol_base + (size_t)sW * RBr * HH;
      const u16* asrc;
      if constexpr (KK == 288) asrc = abuf0 + (size_t)s * RBr * FFX;
      else                     asrc = actv + (size_t)((layer - 1) * 2 + sW) * RBr * 256;
      u16* actvO = actv + (size_t)(layer * 2 + sW) * RBr * 256;

      // ---- GEMM: 32 rows x 96 cols per wave, W from LDS, A from global ----
      f32x4 z4 = {0.f, 0.f, 0.f, 0.f};
      f32x4 acc[2][6];
#pragma unroll
      for (int rf = 0; rf < 2; ++rf)
#pragma unroll
        for (int m = 0; m < 6; ++m) acc[rf][m] = z4;

#pragma unroll
      for (int kc = 0; kc < NCH; ++kc) {
        const int col = kc * 32 + (hi << 3);
        short8 a0, a1;
        if (col < 256) {
          a0 = *(const short8*)&hzR[(ra + fr) * 256 + col];
          a1 = *(const short8*)&hzR[(ra + 16 + fr) * 256 + col];
        } else {
          a0 = *(const short8*)&asrc[(ra + fr) * KA + (col - 256)];
          a1 = *(const short8*)&asrc[(ra + 16 + fr) * KA + (col - 256)];
        }
#pragma unroll
        for (int m = 0; m < 6; ++m) {
          short8 bv = *(const short8*)&Wl[((m * 16 + fr) * SLP + ((kc * 4 + hi) ^ fx)) * 8];
          acc[0][m] = __builtin_amdgcn_mfma_f32_16x16x32_bf16(a0, bv, acc[0][m], 0, 0, 0);
          acc[1][m] = __builtin_amdgcn_mfma_f32_16x16x32_bf16(a1, bv, acc[1][m], 0, 0, 0);
        }
      }

      // ---- fused pointwise epilogue ----
#pragma unroll
      for (int rf = 0; rf < 2; ++rf) {
#pragma unroll
        for (int q = 0; q < 4; ++q) {
          int row = ra + rf * 16 + rsub + q;   // C layout: row=(lane>>4)*4+reg
          int g = row >> 6, b = row & 63;
          float msk = (g <= s && s < RR) ? 1.0f : 0.0f;
          float ur  = sigmoidf_(acc[rf][0][q] + msk * bia[0]);
          float orw = sigmoidf_(acc[rf][1][q] + msk * bia[1]);
          float uc  = sigmoidf_(acc[rf][2][q] + msk * bia[2]);
          float oc  = sigmoidf_(acc[rf][3][q] + msk * bia[3]);
          float ir  = tanhf_(acc[rf][4][q] + msk * bia[4]);
          float ic  = tanhf_(acc[rf][5][q] + msk * bia[5]);
          float hr_o = hr_reg[rf][q];
          float hc_o = hcolR[row * HH + j];
          float hr_n = tanhf_((1.0f - ur) * hr_o + ur * ir) * orw;
          float hc_n = tanhf_((1.0f - uc) * hc_o + uc * ic) * oc;
          hr_reg[rf][q] = hr_n;
          int rp = (((g + 1) & (RR - 1)) << 6) + b;   // col hidden rolls to next group
          hcolW[rp * HH + j] = hc_n;
          hzW[row * 256 + j] = f2b(hr_n);
          hzW[rp * 256 + HH + j] = f2b(hc_n);
          if (layer == 2) {
            out[((size_t)row * LLX + s) * 256 + j] = hr_n;
            out[((size_t)row * LLX + s) * 256 + HH + j] = hc_n;
          } else {
            actvO[row * 256 + j] = f2b(hr_n);
            actvO[row * 256 + HH + j] = f2b(hc_n);
          }
          if (s - g == OO - 1)
            hid_row[((size_t)(b * NLAY + layer) * RR + g) * HH + j] = hr_n;
          if (g == RR - 1 && s >= RR - 1)
            hid_col[((size_t)(b * NLAY + layer) * OO + (s - (RR - 1))) * HH + j] = hc_n;
        }
      }
    }
    grid_barrier(bar, (uint32_t)NBLOCKS * (uint32_t)(t + 1));
  }
}

// ---------------- the persistent kernel ----------------
// Block mapping: bx = jblk*24 + (layer*8 + rowblk). Since 24 % 8 == 0, all 8
// jblk-duplicates of one (layer,rowblk) share bx%8 -> same XCD (round-robin
// dispatch) -> the shared A-panel is fetched from L3 once and L2-hit 7 times.
__global__ __launch_bounds__(512) void k_persist(char* __restrict__ ws,
                                                 const float* __restrict__ Wf,
                                                 const float* __restrict__ Wo,
                                                 const float* __restrict__ Bias,
                                                 float* __restrict__ out) {
  __shared__ u16 Wl[96 * 64 * 8];   // 98,304 B; 1 block/CU by LDS capacity
  const int bx = blockIdx.x;
  const int jblk = bx / 24;
  const int c = bx % 24;
  const int layer = c >> 3;
  const int rowblk = c & 7;
  const float* bias_l = Bias + layer * N6;
  if (layer == 0) {
    persist_body<288>(ws, Wf, bias_l, out, 0, rowblk, jblk, Wl);
  } else {
    const float* Wsrc = Wo + (size_t)(layer - 1) * N6 * 512;
    persist_body<512>(ws, Wsrc, bias_l, out, layer, rowblk, jblk, Wl);
  }
}

extern "C" void kernel_launch(void* const* d_in, const int* in_sizes, int n_in,
                              void* d_out, int out_size, void* d_ws, size_t ws_size,
                              hipStream_t stream) {
  const float* inp  = (const float*)d_in[0];
  const float* Wf   = (const float*)d_in[1];
  const float* Wo   = (const float*)d_in[2];
  const float* Bias = (const float*)d_in[3];
  float* out = (float*)d_out;
  char* ws = (char*)d_ws;
  (void)in_sizes; (void)n_in; (void)out_size; (void)ws_size;

  k_prep_input<<<(LLX * RBr * FFX) / 256, 256, 0, stream>>>(inp, (u16*)(ws + OFF_ABUF0));
  k_zero<<<2048, 256, 0, stream>>>((uint32_t*)(ws + OFF_HZ), SZ_STATE / 4);
  k_persist<<<NBLOCKS, 512, 0, stream>>>(ws, Wf, Wo, Bias, out);
}

// Round 5
// 1087.388 us; speedup vs baseline: 3.2969x; 2.8415x over previous
//
#include <hip/hip_runtime.h>
#include <stdint.h>

#define HH   128
#define NLAY 3
#define RR   32
#define OO   48
#define BBX  64
#define FFX  32
#define LLX  (RR + OO - 1)    /* 79 */
#define RBr  (RR * BBX)       /* 2048 */
#define N6   (6 * HH)         /* 768 */
#define TSTEPS (LLX + NLAY - 1)  /* 81 */
#define NBLOCKS 192

typedef unsigned short u16;
typedef __attribute__((ext_vector_type(8))) short short8;
typedef __attribute__((ext_vector_type(4))) float f32x4;

// ---- workspace layout ----
#define OFF_ABUF0 ((size_t)0)
#define SZ_ABUF0  ((size_t)LLX * RBr * FFX * 2)
#define OFF_HZ    (OFF_ABUF0 + SZ_ABUF0)
#define SZ_HZ     ((size_t)NLAY * 2 * RBr * 256 * 2)   /* [l][slot][2048][256] bf16 */
#define OFF_BAR   (OFF_HZ + SZ_HZ)
#define SZ_BAR    ((size_t)4096)   /* barG @0, barC[b] @128+b*128, table @2048 */
#define SZ_STATE  (SZ_HZ + SZ_BAR)
#define OFF_ACTV  (OFF_BAR + SZ_BAR)
#define SZ_ACTV   ((size_t)2 * 2 * RBr * 256 * 2)

__device__ __forceinline__ u16 f2b(float x) {
  uint32_t u = __float_as_uint(x);
  return (u16)((u + 0x7FFFu + ((u >> 16) & 1u)) >> 16);
}
__device__ __forceinline__ float sigmoidf_(float x) {
  return 1.0f / (1.0f + __expf(-x));
}
__device__ __forceinline__ float tanhf_(float x) {
  float e = __expf(2.0f * x);
  return 1.0f - 2.0f / (e + 1.0f);
}

__global__ __launch_bounds__(256) void k_prep_input(const float* __restrict__ inp,
                                                    u16* __restrict__ abuf0) {
  int idx = blockIdx.x * 256 + threadIdx.x;
  if (idx >= LLX * RBr * FFX) return;
  int f   = idx & (FFX - 1);
  int row = (idx >> 5) & (RBr - 1);
  int s   = idx / (RBr * FFX);
  int g = row >> 6, b = row & 63;
  int o = s - g;
  float v = (o >= 0 && o < OO) ? inp[((b * RR + g) * OO + o) * FFX + f] : 0.0f;
  abuf0[idx] = f2b(v);
}

__global__ __launch_bounds__(256) void k_zero(uint32_t* __restrict__ p, size_t nwords) {
  size_t i = (size_t)blockIdx.x * 256 + threadIdx.x;
  size_t stride = (size_t)gridDim.x * 256;
  for (; i < nwords; i += stride) p[i] = 0u;
}

// Per-component (24-block) step barrier. light: no fences (intra-XCD coherence
// via write-through L2 + L1 invalidate). heavy: agent fences (placement-safe).
__device__ __forceinline__ void step_barrier(uint32_t* barC, uint32_t target, bool light) {
  __syncthreads();
  if (threadIdx.x == 0) {
    if (!light) __threadfence();
    __hip_atomic_fetch_add(barC, 1u, __ATOMIC_RELAXED, __HIP_MEMORY_SCOPE_AGENT);
    while (__hip_atomic_load(barC, __ATOMIC_RELAXED, __HIP_MEMORY_SCOPE_AGENT) < target)
      __builtin_amdgcn_s_sleep(1);
    if (!light) __threadfence();
  }
  __syncthreads();
  if (light) asm volatile("buffer_inv" ::: "memory");
}

template <int KK>
__device__ __forceinline__ void stage_w(const float* __restrict__ Wsrc, int jblk,
                                        u16* __restrict__ Wl) {
  constexpr int SLOTS = KK / 8;
  constexpr int SLP = (KK == 512) ? 64 : 40;
  for (int e = threadIdx.x; e < 96 * SLOTS; e += 512) {
    int wr = e / SLOTS, sl = e - wr * SLOTS;
    int srow = (wr >> 4) * 128 + jblk * 16 + (wr & 15);
    const float* src = Wsrc + (size_t)srow * KK + sl * 8;
    short8 v;
#pragma unroll
    for (int x = 0; x < 8; ++x) v[x] = (short)f2b(src[x]);
    *(short8*)&Wl[(wr * SLP + (sl ^ (wr & 7))) * 8] = v;
  }
}

template <int KK>
__device__ __forceinline__ void persist_body(char* __restrict__ ws,
                                             const float* __restrict__ Bias_l,
                                             float* __restrict__ out,
                                             int layer, int jblk, int bblk, bool light,
                                             u16* __restrict__ Wl,
                                             float* __restrict__ hcl,
                                             uint32_t* __restrict__ barC) {
  constexpr int KA  = KK - 256;
  constexpr int NCH = KK / 32;
  constexpr int SLP = (KK == 512) ? 64 : 40;
  const int tid = threadIdx.x;
  const int lane = tid & 63, w = tid >> 6;
  const int fr = lane & 15, hi = lane >> 4, fx = fr & 7;

  // A fragment rows: rl -> (gg=rl>>3, bb=rl&7); row = (w*4+gg)*64 + bblk*8 + bb
  const int a0row = (w * 4 + (fr >> 3)) * 64 + bblk * 8 + (fr & 7);
  const int a1row = a0row + 128;
  const int a0hz = a0row * 256 + hi * 8;
  const int a1hz = a1row * 256 + hi * 8;
  const int a0ka = a0row * KA + hi * 8;
  const int a1ka = a1row * KA + hi * 8;
  const int j = jblk * 16 + fr;
  int wb[6];
#pragma unroll
  for (int m = 0; m < 6; ++m) wb[m] = (m * 16 + fr) * SLP * 8;
  float bia[6];
#pragma unroll
  for (int m = 0; m < 6; ++m) bia[m] = Bias_l[m * 128 + j];

  u16*   hz_base = (u16*)(ws + OFF_HZ) + (size_t)layer * 2 * RBr * 256;
  u16*   actv    = (u16*)(ws + OFF_ACTV);
  u16*   abuf0   = (u16*)(ws + OFF_ABUF0);
  float* hid_row = out + (size_t)RBr * LLX * 256;
  float* hid_col = hid_row + (size_t)BBX * NLAY * RR * HH;

  float hr_reg[2][4];
#pragma unroll
  for (int rf = 0; rf < 2; ++rf)
#pragma unroll
    for (int q = 0; q < 4; ++q) hr_reg[rf][q] = 0.0f;

  for (int t = 0; t < TSTEPS; ++t) {
    const int s = t - layer;
    if (s >= 0 && s < LLX) {
      const int sW = s & 1, sR = sW ^ 1;
      const u16* hzR = hz_base + (size_t)sR * RBr * 256;
      u16*       hzW = hz_base + (size_t)sW * RBr * 256;
      const u16* asrc;
      if constexpr (KK == 288) asrc = abuf0 + (size_t)s * RBr * FFX;
      else                     asrc = actv + (size_t)((layer - 1) * 2 + sW) * RBr * 256;
      u16* actvO = actv + (size_t)(layer * 2 + sW) * RBr * 256;
      const float* hcR = hcl + sR * 4096;
      float*       hcW = hcl + sW * 4096;

      f32x4 z4 = {0.f, 0.f, 0.f, 0.f};
      f32x4 acc[2][6];
#pragma unroll
      for (int rf = 0; rf < 2; ++rf)
#pragma unroll
        for (int m = 0; m < 6; ++m) acc[rf][m] = z4;

#pragma unroll
      for (int kc = 0; kc < NCH; ++kc) {
        short8 a0, a1;
        if (kc < 8) {
          a0 = *(const short8*)&hzR[a0hz + kc * 32];
          a1 = *(const short8*)&hzR[a1hz + kc * 32];
        } else if constexpr (KK == 512) {
          a0 = *(const short8*)&asrc[a0ka + (kc - 8) * 32];
          a1 = *(const short8*)&asrc[a1ka + (kc - 8) * 32];
        } else {
          a0 = *(const short8*)&asrc[a0ka];
          a1 = *(const short8*)&asrc[a1ka];
        }
#pragma unroll
        for (int m = 0; m < 6; ++m) {
          short8 bv = *(const short8*)&Wl[wb[m] + (((kc * 4 + hi) ^ fx) << 3)];
          acc[0][m] = __builtin_amdgcn_mfma_f32_16x16x32_bf16(a0, bv, acc[0][m], 0, 0, 0);
          acc[1][m] = __builtin_amdgcn_mfma_f32_16x16x32_bf16(a1, bv, acc[1][m], 0, 0, 0);
        }
      }

      // ---- fused pointwise epilogue ----
#pragma unroll
      for (int rf = 0; rf < 2; ++rf) {
#pragma unroll
        for (int q = 0; q < 4; ++q) {
          const int g  = w * 4 + rf * 2 + (hi >> 1);
          const int lb = (hi & 1) * 4 + q;
          const int b  = bblk * 8 + lb;
          const int row = g * 64 + b;
          const int lrow = g * 8 + lb;
          const int gp = (g + 1) & (RR - 1);
          const int rp = gp * 64 + b;
          const int lrp = gp * 8 + lb;
          float msk = (g <= s && s < RR) ? 1.0f : 0.0f;
          float ur  = sigmoidf_(acc[rf][0][q] + msk * bia[0]);
          float orw = sigmoidf_(acc[rf][1][q] + msk * bia[1]);
          float uc  = sigmoidf_(acc[rf][2][q] + msk * bia[2]);
          float oc  = sigmoidf_(acc[rf][3][q] + msk * bia[3]);
          float ir  = tanhf_(acc[rf][4][q] + msk * bia[4]);
          float ic  = tanhf_(acc[rf][5][q] + msk * bia[5]);
          float hr_o = hr_reg[rf][q];
          float hc_o = hcR[lrow * 16 + fr];
          float hr_n = tanhf_((1.0f - ur) * hr_o + ur * ir) * orw;
          float hc_n = tanhf_((1.0f - uc) * hc_o + uc * ic) * oc;
          hr_reg[rf][q] = hr_n;
          hcW[lrp * 16 + fr] = hc_n;
          hzW[row * 256 + j] = f2b(hr_n);
          hzW[rp * 256 + HH + j] = f2b(hc_n);
          if (layer == 2) {
            out[((size_t)row * LLX + s) * 256 + j] = hr_n;
            out[((size_t)row * LLX + s) * 256 + HH + j] = hc_n;
          } else {
            actvO[row * 256 + j] = f2b(hr_n);
            actvO[row * 256 + HH + j] = f2b(hc_n);
          }
          if (s - g == OO - 1)
            hid_row[((size_t)(b * NLAY + layer) * RR + g) * HH + j] = hr_n;
          if (g == RR - 1 && s >= RR - 1)
            hid_col[((size_t)(b * NLAY + layer) * OO + (s - (RR - 1))) * HH + j] = hc_n;
        }
      }
    }
    step_barrier(barC, 24u * (uint32_t)(t + 1), light);
  }
}

__global__ __launch_bounds__(512) void k_persist(char* __restrict__ ws,
                                                 const float* __restrict__ Wf,
                                                 const float* __restrict__ Wo,
                                                 const float* __restrict__ Bias,
                                                 float* __restrict__ out) {
  __shared__ u16 Wl[49152];       // 96 KiB: W slice, swizzled
  __shared__ float hcl[8192];     // 32 KiB: hc state, double-buffered
  __shared__ uint32_t sh_light;
  const int bx = blockIdx.x;
  const int layer = bx >> 6, jblk = (bx >> 3) & 7, bblk = bx & 7;
  const int tid = threadIdx.x;

  // stage W + zero hc
  if (layer == 0) stage_w<288>(Wf, jblk, Wl);
  else            stage_w<512>(Wo + (size_t)(layer - 1) * N6 * 512, jblk, Wl);
  for (int e = tid; e < 8192; e += 512) hcl[e] = 0.0f;

  // placement check: one-time global heavy barrier + per-component XCD match
  uint32_t xcc;
  asm volatile("s_getreg_b32 %0, hwreg(20, 0, 4)" : "=s"(xcc));
  uint32_t* barG  = (uint32_t*)(ws + OFF_BAR);
  uint32_t* barC  = (uint32_t*)(ws + OFF_BAR + 128 + (size_t)bblk * 128);
  uint32_t* table = (uint32_t*)(ws + OFF_BAR + 2048);
  __syncthreads();
  if (tid == 0) {
    __hip_atomic_store(&table[bx], xcc, __ATOMIC_RELAXED, __HIP_MEMORY_SCOPE_AGENT);
    __hip_atomic_fetch_add(barG, 1u, __ATOMIC_RELEASE, __HIP_MEMORY_SCOPE_AGENT);
    while (__hip_atomic_load(barG, __ATOMIC_ACQUIRE, __HIP_MEMORY_SCOPE_AGENT) < NBLOCKS)
      __builtin_amdgcn_s_sleep(1);
    uint32_t lt = 1u;
    for (int q2 = 0; q2 < 24; ++q2) {
      uint32_t v = __hip_atomic_load(&table[q2 * 8 + bblk], __ATOMIC_RELAXED,
                                     __HIP_MEMORY_SCOPE_AGENT);
      lt &= (v == xcc) ? 1u : 0u;
    }
    sh_light = lt;
  }
  __syncthreads();
  const bool light = (sh_light != 0u);

  const float* bias_l = Bias + layer * N6;
  if (layer == 0)
    persist_body<288>(ws, bias_l, out, 0, jblk, bblk, light, Wl, hcl, barC);
  else
    persist_body<512>(ws, bias_l, out, layer, jblk, bblk, light, Wl, hcl, barC);
}

extern "C" void kernel_launch(void* const* d_in, const int* in_sizes, int n_in,
                              void* d_out, int out_size, void* d_ws, size_t ws_size,
                              hipStream_t stream) {
  const float* inp  = (const float*)d_in[0];
  const float* Wf   = (const float*)d_in[1];
  const float* Wo   = (const float*)d_in[2];
  const float* Bias = (const float*)d_in[3];
  float* out = (float*)d_out;
  char* ws = (char*)d_ws;
  (void)in_sizes; (void)n_in; (void)out_size; (void)ws_size;

  k_prep_input<<<(LLX * RBr * FFX) / 256, 256, 0, stream>>>(inp, (u16*)(ws + OFF_ABUF0));
  k_zero<<<2048, 256, 0, stream>>>((uint32_t*)(ws + OFF_HZ), SZ_STATE / 4);
  k_persist<<<NBLOCKS, 512, 0, stream>>>(ws, Wf, Wo, Bias, out);
}